// Round 1
// baseline (2258.937 us; speedup 1.0000x reference)
//
#include <hip/hip_runtime.h>
#include <math.h>

constexpr int N_NODES = 100000;
constexpr int N_EDGES = 1600000;
constexpr int H       = 128;   // HIDDEN == NUM_FILTERS
constexpr int NG      = 50;    // NUM_GAUSSIANS
constexpr int EPB     = 8;     // edges per block
constexpr int NPB     = 8;     // nodes per block

__device__ __forceinline__ float ssp(float v) {
    // shifted softplus: log(1+exp(v)) - log(2), numerically stable
    return fmaxf(v, 0.0f) + log1pf(expf(-fabsf(v))) - 0.69314718056f;
}

// ---------------- lin1: x = h @ lin1_w  (no bias) ----------------
__global__ __launch_bounds__(128) void lin1_kernel(
    const float* __restrict__ h, const float* __restrict__ w,
    float* __restrict__ x)
{
    __shared__ float hs[NPB][H];
    const int f  = threadIdx.x;
    const int n0 = blockIdx.x * NPB;

    #pragma unroll
    for (int e = 0; e < NPB; ++e) hs[e][f] = h[(n0 + e) * H + f];
    __syncthreads();

    float acc[NPB];
    #pragma unroll
    for (int e = 0; e < NPB; ++e) acc[e] = 0.0f;

    for (int k = 0; k < H; k += 4) {
        float w0 = w[(k + 0) * H + f];
        float w1 = w[(k + 1) * H + f];
        float w2 = w[(k + 2) * H + f];
        float w3 = w[(k + 3) * H + f];
        #pragma unroll
        for (int e = 0; e < NPB; ++e) {
            float4 t4 = *reinterpret_cast<const float4*>(&hs[e][k]);
            acc[e] = fmaf(t4.x, w0, acc[e]);
            acc[e] = fmaf(t4.y, w1, acc[e]);
            acc[e] = fmaf(t4.z, w2, acc[e]);
            acc[e] = fmaf(t4.w, w3, acc[e]);
        }
    }
    #pragma unroll
    for (int e = 0; e < NPB; ++e) x[(n0 + e) * H + f] = acc[e];
}

// ---------------- edge kernel: filter MLP + gather/modulate/scatter ----------------
__global__ __launch_bounds__(128) void edge_kernel(
    const float* __restrict__ pos, const int* __restrict__ ei,
    const float* __restrict__ x,
    const float* __restrict__ w1, const float* __restrict__ b1,
    const float* __restrict__ w2, const float* __restrict__ b2,
    float* __restrict__ agg)
{
    __shared__ float attr_s[EPB][NG];
    __shared__ float t_s[EPB][H];
    __shared__ float d_s[EPB];
    __shared__ float c_s[EPB];
    __shared__ int   row_s[EPB];
    __shared__ int   col_s[EPB];

    const int f  = threadIdx.x;
    const int e0 = blockIdx.x * EPB;

    if (f < EPB) {
        const int e = e0 + f;
        const int r = ei[e];
        const int c = ei[N_EDGES + e];
        row_s[f] = r;
        col_s[f] = c;
        const float dx = pos[3 * r + 0] - pos[3 * c + 0];
        const float dy = pos[3 * r + 1] - pos[3 * c + 1];
        const float dz = pos[3 * r + 2] - pos[3 * c + 2];
        const float d  = sqrtf(dx * dx + dy * dy + dz * dz);
        d_s[f] = d;
        c_s[f] = 0.5f * (cosf(d * 0.31415926535897931f) + 1.0f);  // pi/CUTOFF
    }
    __syncthreads();

    // Gaussian smearing: attr[e][g] = exp(coeff*(d - g*step)^2)
    // step = 10/49, coeff = -0.5/step^2 = -12.005
    for (int i = f; i < EPB * NG; i += 128) {
        const int e = i / NG, g = i - e * NG;
        const float diff = d_s[e] - (float)g * (10.0f / 49.0f);
        attr_s[e][g] = expf(-12.005f * diff * diff);
    }
    __syncthreads();

    // Stage 1: t = ssp(attr @ w1 + b1)
    const float bias1 = b1[f];
    float acc1[EPB];
    #pragma unroll
    for (int e = 0; e < EPB; ++e) acc1[e] = bias1;

    for (int g = 0; g < NG; ++g) {
        const float wv = w1[g * H + f];
        #pragma unroll
        for (int e = 0; e < EPB; ++e) acc1[e] = fmaf(attr_s[e][g], wv, acc1[e]);
    }
    #pragma unroll
    for (int e = 0; e < EPB; ++e) t_s[e][f] = ssp(acc1[e]);
    __syncthreads();

    // Stage 2: W = (t @ w2 + b2) * C
    const float bias2 = b2[f];
    float acc2[EPB];
    #pragma unroll
    for (int e = 0; e < EPB; ++e) acc2[e] = bias2;

    for (int k = 0; k < H; k += 4) {
        float wA = w2[(k + 0) * H + f];
        float wB = w2[(k + 1) * H + f];
        float wC = w2[(k + 2) * H + f];
        float wD = w2[(k + 3) * H + f];
        #pragma unroll
        for (int e = 0; e < EPB; ++e) {
            float4 t4 = *reinterpret_cast<const float4*>(&t_s[e][k]);
            acc2[e] = fmaf(t4.x, wA, acc2[e]);
            acc2[e] = fmaf(t4.y, wB, acc2[e]);
            acc2[e] = fmaf(t4.z, wC, acc2[e]);
            acc2[e] = fmaf(t4.w, wD, acc2[e]);
        }
    }

    // Epilogue: msgs = x[col] * (W * C); scatter-add into agg[row]
    #pragma unroll
    for (int e = 0; e < EPB; ++e) {
        const float Wf  = acc2[e] * c_s[e];
        const float msg = x[col_s[e] * H + f] * Wf;
        atomicAdd(&agg[row_s[e] * H + f], msg);
    }
}

// ---------------- final: out = ssp(agg @ lin2_w + lin2_b) @ lin_w + lin_b ----------------
__global__ __launch_bounds__(128) void final_kernel(
    const float* __restrict__ agg,
    const float* __restrict__ w2l, const float* __restrict__ b2l,
    const float* __restrict__ wl,  const float* __restrict__ bl,
    float* __restrict__ out)
{
    __shared__ float as[NPB][H];
    __shared__ float ts[NPB][H];
    const int f  = threadIdx.x;
    const int n0 = blockIdx.x * NPB;

    #pragma unroll
    for (int e = 0; e < NPB; ++e) as[e][f] = agg[(n0 + e) * H + f];
    __syncthreads();

    const float bias2 = b2l[f];
    float acc[NPB];
    #pragma unroll
    for (int e = 0; e < NPB; ++e) acc[e] = bias2;

    for (int k = 0; k < H; k += 4) {
        float wA = w2l[(k + 0) * H + f];
        float wB = w2l[(k + 1) * H + f];
        float wC = w2l[(k + 2) * H + f];
        float wD = w2l[(k + 3) * H + f];
        #pragma unroll
        for (int e = 0; e < NPB; ++e) {
            float4 t4 = *reinterpret_cast<const float4*>(&as[e][k]);
            acc[e] = fmaf(t4.x, wA, acc[e]);
            acc[e] = fmaf(t4.y, wB, acc[e]);
            acc[e] = fmaf(t4.z, wC, acc[e]);
            acc[e] = fmaf(t4.w, wD, acc[e]);
        }
    }
    #pragma unroll
    for (int e = 0; e < NPB; ++e) ts[e][f] = ssp(acc[e]);
    __syncthreads();

    const float biasL = bl[f];
    float acc2[NPB];
    #pragma unroll
    for (int e = 0; e < NPB; ++e) acc2[e] = biasL;

    for (int k = 0; k < H; k += 4) {
        float wA = wl[(k + 0) * H + f];
        float wB = wl[(k + 1) * H + f];
        float wC = wl[(k + 2) * H + f];
        float wD = wl[(k + 3) * H + f];
        #pragma unroll
        for (int e = 0; e < NPB; ++e) {
            float4 t4 = *reinterpret_cast<const float4*>(&ts[e][k]);
            acc2[e] = fmaf(t4.x, wA, acc2[e]);
            acc2[e] = fmaf(t4.y, wB, acc2[e]);
            acc2[e] = fmaf(t4.z, wC, acc2[e]);
            acc2[e] = fmaf(t4.w, wD, acc2[e]);
        }
    }
    #pragma unroll
    for (int e = 0; e < NPB; ++e) out[(n0 + e) * H + f] = acc2[e];
}

extern "C" void kernel_launch(void* const* d_in, const int* in_sizes, int n_in,
                              void* d_out, int out_size, void* d_ws, size_t ws_size,
                              hipStream_t stream) {
    const float* h      = (const float*)d_in[0];
    const float* pos    = (const float*)d_in[1];
    const int*   ei     = (const int*)  d_in[2];
    const float* mlp_w1 = (const float*)d_in[3];
    const float* mlp_b1 = (const float*)d_in[4];
    const float* mlp_w2 = (const float*)d_in[5];
    const float* mlp_b2 = (const float*)d_in[6];
    const float* lin1_w = (const float*)d_in[7];
    const float* lin2_w = (const float*)d_in[8];
    const float* lin2_b = (const float*)d_in[9];
    const float* lin_w  = (const float*)d_in[10];
    const float* lin_b  = (const float*)d_in[11];

    float* out = (float*)d_out;
    float* agg = (float*)d_ws;          // [N, H] accumulator
    float* x   = out;                    // reuse d_out as scratch for lin1 output

    hipMemsetAsync(agg, 0, (size_t)N_NODES * H * sizeof(float), stream);
    lin1_kernel<<<N_NODES / NPB, 128, 0, stream>>>(h, lin1_w, x);
    edge_kernel<<<N_EDGES / EPB, 128, 0, stream>>>(pos, ei, x, mlp_w1, mlp_b1,
                                                   mlp_w2, mlp_b2, agg);
    final_kernel<<<N_NODES / NPB, 128, 0, stream>>>(agg, lin2_w, lin2_b,
                                                    lin_w, lin_b, out);
}

// Round 2
// 1036.543 us; speedup vs baseline: 2.1793x; 2.1793x over previous
//
#include <hip/hip_runtime.h>
#include <math.h>

constexpr int N_NODES = 100000;
constexpr int N_EDGES = 1600000;
constexpr int H       = 128;   // HIDDEN == NUM_FILTERS
constexpr int NG      = 50;    // NUM_GAUSSIANS
constexpr int EPT     = 32;    // edges per tile
constexpr int NT      = N_EDGES / EPT;  // 50000 tiles
constexpr int NPB     = 8;     // nodes per block (lin1/final)

typedef _Float16 f16x8 __attribute__((ext_vector_type(8)));
typedef float    f32x4 __attribute__((ext_vector_type(4)));

__device__ __forceinline__ float ssp(float v) {
    // shifted softplus: log(1+exp(v)) - log(2)
    return fmaxf(v, 0.0f) + logf(1.0f + expf(-fabsf(v))) - 0.69314718056f;
}

// ---------------- lin1: x = h @ lin1_w  (no bias) ----------------
__global__ __launch_bounds__(128) void lin1_kernel(
    const float* __restrict__ h, const float* __restrict__ w,
    float* __restrict__ x)
{
    __shared__ float hs[NPB][H];
    const int f  = threadIdx.x;
    const int n0 = blockIdx.x * NPB;

    #pragma unroll
    for (int e = 0; e < NPB; ++e) hs[e][f] = h[(n0 + e) * H + f];
    __syncthreads();

    float acc[NPB];
    #pragma unroll
    for (int e = 0; e < NPB; ++e) acc[e] = 0.0f;

    for (int k = 0; k < H; k += 4) {
        float w0 = w[(k + 0) * H + f];
        float w1 = w[(k + 1) * H + f];
        float w2 = w[(k + 2) * H + f];
        float w3 = w[(k + 3) * H + f];
        #pragma unroll
        for (int e = 0; e < NPB; ++e) {
            float4 t4 = *reinterpret_cast<const float4*>(&hs[e][k]);
            acc[e] = fmaf(t4.x, w0, acc[e]);
            acc[e] = fmaf(t4.y, w1, acc[e]);
            acc[e] = fmaf(t4.z, w2, acc[e]);
            acc[e] = fmaf(t4.w, w3, acc[e]);
        }
    }
    #pragma unroll
    for (int e = 0; e < NPB; ++e) x[(n0 + e) * H + f] = acc[e];
}

// ---------------- edge kernel: MFMA filter MLP + gather/modulate/scatter ----------------
__global__ __launch_bounds__(256) void edge_kernel(
    const float* __restrict__ pos, const int* __restrict__ ei,
    const float* __restrict__ x,
    const float* __restrict__ w1, const float* __restrict__ b1,
    const float* __restrict__ w2, const float* __restrict__ b2,
    float* __restrict__ agg)
{
    __shared__ alignas(16) _Float16 t_lds[EPT * H];  // XOR-swizzled
    __shared__ float d_s[EPT], c_s[EPT];
    __shared__ int   row_s[EPT], col_s[EPT];

    const int tid = threadIdx.x;
    const int w   = tid >> 6;   // wave 0..3 -> filters w*32 .. w*32+31
    const int l   = tid & 63;
    const int lhi = l >> 4;     // 0..3
    const int llo = l & 15;     // 0..15

    constexpr float GSTEP = 10.0f / 49.0f;
    constexpr float GCOEF = -12.005f;            // -0.5/GSTEP^2
    constexpr float PIC   = 0.31415926535897931f; // pi/CUTOFF

    // ---- weight fragments, loaded once per block into registers ----
    // B layout for mfma_16x16x32: lane holds B[k = ks*32 + lhi*8 + i][n = llo-based]
    f16x8 b1f[2][2];  // [nf][ks], stage1 K=64 (padded)
    #pragma unroll
    for (int nf = 0; nf < 2; ++nf) {
        const int n = w * 32 + nf * 16 + llo;
        #pragma unroll
        for (int ks = 0; ks < 2; ++ks) {
            #pragma unroll
            for (int i = 0; i < 8; ++i) {
                const int k = ks * 32 + lhi * 8 + i;
                b1f[nf][ks][i] = (k < NG) ? (_Float16)w1[k * H + n] : (_Float16)0.0f;
            }
        }
    }
    f16x8 b2f[2][4];  // [nf][ks], stage2 K=128
    #pragma unroll
    for (int nf = 0; nf < 2; ++nf) {
        const int n = w * 32 + nf * 16 + llo;
        #pragma unroll
        for (int ks = 0; ks < 4; ++ks) {
            #pragma unroll
            for (int i = 0; i < 8; ++i) {
                const int k = ks * 32 + lhi * 8 + i;
                b2f[nf][ks][i] = (_Float16)w2[k * H + n];
            }
        }
    }
    const float b1v[2] = { b1[w * 32 + llo], b1[w * 32 + 16 + llo] };
    const float b2v[2] = { b2[w * 32 + llo], b2[w * 32 + 16 + llo] };

    const f32x4 zero4 = {0.0f, 0.0f, 0.0f, 0.0f};

    // ---- software-pipelined edge setup (threads 0..31 own one edge each) ----
    int rN = 0, cN = 0; float dN = 0.0f, ccN = 0.0f;
    auto load_setup = [&](int t, int& r, int& c, float& d, float& cc) {
        const int e = t * EPT + tid;
        r = ei[e];
        c = ei[N_EDGES + e];
        const float dx = pos[3 * r + 0] - pos[3 * c + 0];
        const float dy = pos[3 * r + 1] - pos[3 * c + 1];
        const float dz = pos[3 * r + 2] - pos[3 * c + 2];
        d  = sqrtf(dx * dx + dy * dy + dz * dz);
        cc = 0.5f * cosf(d * PIC) + 0.5f;
    };
    if (tid < EPT && (int)blockIdx.x < NT)
        load_setup(blockIdx.x, rN, cN, dN, ccN);

    for (int t = blockIdx.x; t < NT; t += gridDim.x) {
        __syncthreads();   // prev iter done with d_s/c_s/row/col and t_lds
        if (tid < EPT) {
            row_s[tid] = rN; col_s[tid] = cN;
            d_s[tid]   = dN; c_s[tid]   = ccN;
        }
        __syncthreads();
        const int tn = t + gridDim.x;
        if (tid < EPT && tn < NT)
            load_setup(tn, rN, cN, dN, ccN);  // overlaps with compute below

        // ---- stage 1: c1 = attr @ w1, attr computed in registers ----
        f32x4 c1[2][2];   // [msub][nf]
        #pragma unroll
        for (int m = 0; m < 2; ++m)
            #pragma unroll
            for (int nf = 0; nf < 2; ++nf) c1[m][nf] = zero4;

        #pragma unroll
        for (int msub = 0; msub < 2; ++msub) {
            const float de = d_s[msub * 16 + llo];  // A row = llo
            #pragma unroll
            for (int ks = 0; ks < 2; ++ks) {
                f16x8 a1;
                #pragma unroll
                for (int i = 0; i < 8; ++i) {
                    const int g = ks * 32 + lhi * 8 + i;
                    const float diff = de - (float)g * GSTEP;
                    const float v = (g < NG) ? expf(GCOEF * diff * diff) : 0.0f;
                    a1[i] = (_Float16)v;
                }
                #pragma unroll
                for (int nf = 0; nf < 2; ++nf)
                    c1[msub][nf] = __builtin_amdgcn_mfma_f32_16x16x32_f16(
                        a1, b1f[nf][ks], c1[msub][nf], 0, 0, 0);
            }
        }

        // ---- bias + ssp -> t_lds (fp16, XOR-swizzled rows) ----
        #pragma unroll
        for (int msub = 0; msub < 2; ++msub)
            #pragma unroll
            for (int nf = 0; nf < 2; ++nf)
                #pragma unroll
                for (int j = 0; j < 4; ++j) {
                    const int edge = msub * 16 + lhi * 4 + j;  // C row
                    const int filt = w * 32 + nf * 16 + llo;   // C col
                    const float tv = ssp(c1[msub][nf][j] + b1v[nf]);
                    unsigned off = (unsigned)(edge * H + filt) * 2u;
                    off ^= (unsigned)((edge & 7) << 4);
                    *reinterpret_cast<_Float16*>(
                        reinterpret_cast<char*>(t_lds) + off) = (_Float16)tv;
                }
        __syncthreads();

        // ---- stage 2: c2 = t @ w2 ----
        f32x4 c2[2][2];
        #pragma unroll
        for (int m = 0; m < 2; ++m)
            #pragma unroll
            for (int nf = 0; nf < 2; ++nf) c2[m][nf] = zero4;

        #pragma unroll
        for (int ks = 0; ks < 4; ++ks) {
            f16x8 a2[2];
            #pragma unroll
            for (int msub = 0; msub < 2; ++msub) {
                const int edge = msub * 16 + llo;  // A row
                unsigned off = (unsigned)(edge * H) * 2u
                             + (unsigned)(ks * 64 + lhi * 16);
                off ^= (unsigned)((edge & 7) << 4);
                a2[msub] = *reinterpret_cast<const f16x8*>(
                    reinterpret_cast<const char*>(t_lds) + off);
            }
            #pragma unroll
            for (int msub = 0; msub < 2; ++msub)
                #pragma unroll
                for (int nf = 0; nf < 2; ++nf)
                    c2[msub][nf] = __builtin_amdgcn_mfma_f32_16x16x32_f16(
                        a2[msub], b2f[nf][ks], c2[msub][nf], 0, 0, 0);
        }

        // ---- epilogue: W = (c2+b2)*C; msg = x[col]*W; atomic agg[row] ----
        #pragma unroll
        for (int msub = 0; msub < 2; ++msub)
            #pragma unroll
            for (int j = 0; j < 4; ++j) {
                const int edge = msub * 16 + lhi * 4 + j;
                const float cc   = c_s[edge];
                const int   colv = col_s[edge];
                const int   rowv = row_s[edge];
                #pragma unroll
                for (int nf = 0; nf < 2; ++nf) {
                    const int filt = w * 32 + nf * 16 + llo;
                    const float W   = (c2[msub][nf][j] + b2v[nf]) * cc;
                    const float msg = x[(size_t)colv * H + filt] * W;
                    atomicAdd(&agg[(size_t)rowv * H + filt], msg);
                }
            }
    }
}

// ---------------- final: out = ssp(agg @ lin2_w + lin2_b) @ lin_w + lin_b ----------------
__global__ __launch_bounds__(128) void final_kernel(
    const float* __restrict__ agg,
    const float* __restrict__ w2l, const float* __restrict__ b2l,
    const float* __restrict__ wl,  const float* __restrict__ bl,
    float* __restrict__ out)
{
    __shared__ float as[NPB][H];
    __shared__ float ts[NPB][H];
    const int f  = threadIdx.x;
    const int n0 = blockIdx.x * NPB;

    #pragma unroll
    for (int e = 0; e < NPB; ++e) as[e][f] = agg[(n0 + e) * H + f];
    __syncthreads();

    const float bias2 = b2l[f];
    float acc[NPB];
    #pragma unroll
    for (int e = 0; e < NPB; ++e) acc[e] = bias2;

    for (int k = 0; k < H; k += 4) {
        float wA = w2l[(k + 0) * H + f];
        float wB = w2l[(k + 1) * H + f];
        float wC = w2l[(k + 2) * H + f];
        float wD = w2l[(k + 3) * H + f];
        #pragma unroll
        for (int e = 0; e < NPB; ++e) {
            float4 t4 = *reinterpret_cast<const float4*>(&as[e][k]);
            acc[e] = fmaf(t4.x, wA, acc[e]);
            acc[e] = fmaf(t4.y, wB, acc[e]);
            acc[e] = fmaf(t4.z, wC, acc[e]);
            acc[e] = fmaf(t4.w, wD, acc[e]);
        }
    }
    #pragma unroll
    for (int e = 0; e < NPB; ++e) ts[e][f] = ssp(acc[e]);
    __syncthreads();

    const float biasL = bl[f];
    float acc2[NPB];
    #pragma unroll
    for (int e = 0; e < NPB; ++e) acc2[e] = biasL;

    for (int k = 0; k < H; k += 4) {
        float wA = wl[(k + 0) * H + f];
        float wB = wl[(k + 1) * H + f];
        float wC = wl[(k + 2) * H + f];
        float wD = wl[(k + 3) * H + f];
        #pragma unroll
        for (int e = 0; e < NPB; ++e) {
            float4 t4 = *reinterpret_cast<const float4*>(&ts[e][k]);
            acc2[e] = fmaf(t4.x, wA, acc2[e]);
            acc2[e] = fmaf(t4.y, wB, acc2[e]);
            acc2[e] = fmaf(t4.z, wC, acc2[e]);
            acc2[e] = fmaf(t4.w, wD, acc2[e]);
        }
    }
    #pragma unroll
    for (int e = 0; e < NPB; ++e) out[(n0 + e) * H + f] = acc2[e];
}

extern "C" void kernel_launch(void* const* d_in, const int* in_sizes, int n_in,
                              void* d_out, int out_size, void* d_ws, size_t ws_size,
                              hipStream_t stream) {
    const float* h      = (const float*)d_in[0];
    const float* pos    = (const float*)d_in[1];
    const int*   ei     = (const int*)  d_in[2];
    const float* mlp_w1 = (const float*)d_in[3];
    const float* mlp_b1 = (const float*)d_in[4];
    const float* mlp_w2 = (const float*)d_in[5];
    const float* mlp_b2 = (const float*)d_in[6];
    const float* lin1_w = (const float*)d_in[7];
    const float* lin2_w = (const float*)d_in[8];
    const float* lin2_b = (const float*)d_in[9];
    const float* lin_w  = (const float*)d_in[10];
    const float* lin_b  = (const float*)d_in[11];

    float* out = (float*)d_out;
    float* agg = (float*)d_ws;   // [N, H] accumulator
    float* x   = out;            // reuse d_out as scratch for lin1 output

    hipMemsetAsync(agg, 0, (size_t)N_NODES * H * sizeof(float), stream);
    lin1_kernel<<<N_NODES / NPB, 128, 0, stream>>>(h, lin1_w, x);
    edge_kernel<<<2560, 256, 0, stream>>>(pos, ei, x, mlp_w1, mlp_b1,
                                          mlp_w2, mlp_b2, agg);
    final_kernel<<<N_NODES / NPB, 128, 0, stream>>>(agg, lin2_w, lin2_b,
                                                    lin_w, lin_b, out);
}

// Round 3
// 879.579 us; speedup vs baseline: 2.5682x; 1.1785x over previous
//
#include <hip/hip_runtime.h>
#include <math.h>

constexpr int N_NODES = 100000;
constexpr int N_EDGES = 1600000;
constexpr int H       = 128;   // HIDDEN == NUM_FILTERS
constexpr int NG      = 50;    // NUM_GAUSSIANS
constexpr int EPT     = 32;    // edges per tile
constexpr int NT      = N_EDGES / EPT;  // 50000 tiles
constexpr int NPB     = 8;     // nodes per block (lin1/final)

typedef _Float16 f16x8 __attribute__((ext_vector_type(8)));
typedef float    f32x4 __attribute__((ext_vector_type(4)));

__device__ __forceinline__ float ssp_fast(float v) {
    // shifted softplus: log(1+exp(v)) - log(2), fast intrinsics
    return fmaxf(v, 0.0f) + __logf(1.0f + __expf(-fabsf(v))) - 0.69314718056f;
}

// ---------------- lin1: x = h @ lin1_w  (no bias) ----------------
__global__ __launch_bounds__(128) void lin1_kernel(
    const float* __restrict__ h, const float* __restrict__ w,
    float* __restrict__ x)
{
    __shared__ float hs[NPB][H];
    const int f  = threadIdx.x;
    const int n0 = blockIdx.x * NPB;

    #pragma unroll
    for (int e = 0; e < NPB; ++e) hs[e][f] = h[(n0 + e) * H + f];
    __syncthreads();

    float acc[NPB];
    #pragma unroll
    for (int e = 0; e < NPB; ++e) acc[e] = 0.0f;

    for (int k = 0; k < H; k += 4) {
        float w0 = w[(k + 0) * H + f];
        float w1 = w[(k + 1) * H + f];
        float w2 = w[(k + 2) * H + f];
        float w3 = w[(k + 3) * H + f];
        #pragma unroll
        for (int e = 0; e < NPB; ++e) {
            float4 t4 = *reinterpret_cast<const float4*>(&hs[e][k]);
            acc[e] = fmaf(t4.x, w0, acc[e]);
            acc[e] = fmaf(t4.y, w1, acc[e]);
            acc[e] = fmaf(t4.z, w2, acc[e]);
            acc[e] = fmaf(t4.w, w3, acc[e]);
        }
    }
    #pragma unroll
    for (int e = 0; e < NPB; ++e) x[(n0 + e) * H + f] = acc[e];
}

// ---------------- edge kernel: MFMA filter MLP + gather/modulate/scatter ----------------
__global__ __launch_bounds__(256) void edge_kernel(
    const float* __restrict__ pos, const int* __restrict__ ei,
    const float* __restrict__ x,
    const float* __restrict__ w1, const float* __restrict__ b1,
    const float* __restrict__ w2, const float* __restrict__ b2,
    float* __restrict__ agg)
{
    __shared__ alignas(16) _Float16 t_lds[EPT * H];  // XOR-swizzled
    __shared__ float d_s[EPT], c_s[EPT];
    __shared__ int   row_s[EPT], col_s[EPT];

    const int tid = threadIdx.x;
    const int w   = tid >> 6;   // wave 0..3 -> filters w*32 .. w*32+31
    const int l   = tid & 63;
    const int lhi = l >> 4;     // 0..3
    const int llo = l & 15;     // 0..15

    constexpr float GSTEP = 10.0f / 49.0f;
    constexpr float GCOEF = -12.005f;            // -0.5/GSTEP^2
    constexpr float PIC   = 0.31415926535897931f; // pi/CUTOFF

    // ---- weight fragments, loaded once per block into registers ----
    f16x8 b1f[2][2];  // [nf][ks], stage1 K=64 (padded)
    #pragma unroll
    for (int nf = 0; nf < 2; ++nf) {
        const int n = w * 32 + nf * 16 + llo;
        #pragma unroll
        for (int ks = 0; ks < 2; ++ks) {
            #pragma unroll
            for (int i = 0; i < 8; ++i) {
                const int k = ks * 32 + lhi * 8 + i;
                b1f[nf][ks][i] = (k < NG) ? (_Float16)w1[k * H + n] : (_Float16)0.0f;
            }
        }
    }
    f16x8 b2f[2][4];  // [nf][ks], stage2 K=128
    #pragma unroll
    for (int nf = 0; nf < 2; ++nf) {
        const int n = w * 32 + nf * 16 + llo;
        #pragma unroll
        for (int ks = 0; ks < 4; ++ks) {
            #pragma unroll
            for (int i = 0; i < 8; ++i) {
                const int k = ks * 32 + lhi * 8 + i;
                b2f[nf][ks][i] = (_Float16)w2[k * H + n];
            }
        }
    }
    const float b1v[2] = { b1[w * 32 + llo], b1[w * 32 + 16 + llo] };
    const float b2v[2] = { b2[w * 32 + llo], b2[w * 32 + 16 + llo] };

    const f32x4 zero4 = {0.0f, 0.0f, 0.0f, 0.0f};

    // ---- software-pipelined edge setup (threads 0..31 own one edge each) ----
    int rN = 0, cN = 0; float dN = 0.0f, ccN = 0.0f;
    auto load_setup = [&](int t, int& r, int& c, float& d, float& cc) {
        const int e = t * EPT + tid;
        r = ei[e];
        c = ei[N_EDGES + e];
        const float dx = pos[3 * r + 0] - pos[3 * c + 0];
        const float dy = pos[3 * r + 1] - pos[3 * c + 1];
        const float dz = pos[3 * r + 2] - pos[3 * c + 2];
        d  = sqrtf(dx * dx + dy * dy + dz * dz);
        cc = 0.5f * cosf(d * PIC) + 0.5f;
    };
    if (tid < EPT) load_setup(blockIdx.x, rN, cN, dN, ccN);

    for (int t = blockIdx.x; t < NT; t += gridDim.x) {
        __syncthreads();   // prev iter done with t_lds and smem metadata
        if (tid < EPT) {
            row_s[tid] = rN; col_s[tid] = cN;
            d_s[tid]   = dN; c_s[tid]   = ccN;
        }
        __syncthreads();

        // ---- x-gather prefetch: issue early, consume in epilogue ----
        // 32-bit indices: max = 99999*128+127 = 12.8M < 2^24
        float xv[2][4][2];
        #pragma unroll
        for (int msub = 0; msub < 2; ++msub)
            #pragma unroll
            for (int j = 0; j < 4; ++j) {
                const int edge = msub * 16 + lhi * 4 + j;
                const int cbase = col_s[edge] * H + w * 32 + llo;
                #pragma unroll
                for (int nf = 0; nf < 2; ++nf)
                    xv[msub][j][nf] = x[cbase + nf * 16];
            }

        const int tn = t + gridDim.x;
        if (tid < EPT && tn < NT)
            load_setup(tn, rN, cN, dN, ccN);  // overlaps with compute below

        // ---- stage 1: c1 = attr @ w1, attr computed in registers ----
        f32x4 c1[2][2];   // [msub][nf]
        #pragma unroll
        for (int m = 0; m < 2; ++m)
            #pragma unroll
            for (int nf = 0; nf < 2; ++nf) c1[m][nf] = zero4;

        #pragma unroll
        for (int msub = 0; msub < 2; ++msub) {
            const float de = d_s[msub * 16 + llo];  // A row = llo
            #pragma unroll
            for (int ks = 0; ks < 2; ++ks) {
                f16x8 a1;
                #pragma unroll
                for (int i = 0; i < 8; ++i) {
                    const int g = ks * 32 + lhi * 8 + i;
                    const float diff = de - (float)g * GSTEP;
                    // padded g>=50: exponent <= -211 -> underflows to 0, matches zero B
                    a1[i] = (_Float16)__expf(GCOEF * diff * diff);
                }
                #pragma unroll
                for (int nf = 0; nf < 2; ++nf)
                    c1[msub][nf] = __builtin_amdgcn_mfma_f32_16x16x32_f16(
                        a1, b1f[nf][ks], c1[msub][nf], 0, 0, 0);
            }
        }

        // ---- bias + ssp -> t_lds (fp16, XOR-swizzled rows) ----
        #pragma unroll
        for (int msub = 0; msub < 2; ++msub)
            #pragma unroll
            for (int nf = 0; nf < 2; ++nf)
                #pragma unroll
                for (int j = 0; j < 4; ++j) {
                    const int edge = msub * 16 + lhi * 4 + j;  // C row
                    const int filt = w * 32 + nf * 16 + llo;   // C col
                    const float tv = ssp_fast(c1[msub][nf][j] + b1v[nf]);
                    unsigned off = (unsigned)(edge * H + filt) * 2u;
                    off ^= (unsigned)((edge & 7) << 4);
                    *reinterpret_cast<_Float16*>(
                        reinterpret_cast<char*>(t_lds) + off) = (_Float16)tv;
                }
        __syncthreads();

        // ---- stage 2: c2 = t @ w2 ----
        f32x4 c2[2][2];
        #pragma unroll
        for (int m = 0; m < 2; ++m)
            #pragma unroll
            for (int nf = 0; nf < 2; ++nf) c2[m][nf] = zero4;

        #pragma unroll
        for (int ks = 0; ks < 4; ++ks) {
            f16x8 a2[2];
            #pragma unroll
            for (int msub = 0; msub < 2; ++msub) {
                const int edge = msub * 16 + llo;  // A row
                unsigned off = (unsigned)(edge * H) * 2u
                             + (unsigned)(ks * 64 + lhi * 16);
                off ^= (unsigned)((edge & 7) << 4);
                a2[msub] = *reinterpret_cast<const f16x8*>(
                    reinterpret_cast<const char*>(t_lds) + off);
            }
            #pragma unroll
            for (int msub = 0; msub < 2; ++msub)
                #pragma unroll
                for (int nf = 0; nf < 2; ++nf)
                    c2[msub][nf] = __builtin_amdgcn_mfma_f32_16x16x32_f16(
                        a2[msub], b2f[nf][ks], c2[msub][nf], 0, 0, 0);
        }

        // ---- epilogue: W = (c2+b2)*C; msg = xv*W; atomic agg[row] ----
        #pragma unroll
        for (int msub = 0; msub < 2; ++msub)
            #pragma unroll
            for (int j = 0; j < 4; ++j) {
                const int edge = msub * 16 + lhi * 4 + j;
                const float cc   = c_s[edge];
                const int   rbase = row_s[edge] * H + w * 32 + llo;
                #pragma unroll
                for (int nf = 0; nf < 2; ++nf) {
                    const float W   = (c2[msub][nf][j] + b2v[nf]) * cc;
                    const float msg = xv[msub][j][nf] * W;
                    atomicAdd(&agg[rbase + nf * 16], msg);
                }
            }
    }
}

// ---------------- final: out = ssp(agg @ lin2_w + lin2_b) @ lin_w + lin_b ----------------
__global__ __launch_bounds__(128) void final_kernel(
    const float* __restrict__ agg,
    const float* __restrict__ w2l, const float* __restrict__ b2l,
    const float* __restrict__ wl,  const float* __restrict__ bl,
    float* __restrict__ out)
{
    __shared__ float as[NPB][H];
    __shared__ float ts[NPB][H];
    const int f  = threadIdx.x;
    const int n0 = blockIdx.x * NPB;

    #pragma unroll
    for (int e = 0; e < NPB; ++e) as[e][f] = agg[(n0 + e) * H + f];
    __syncthreads();

    const float bias2 = b2l[f];
    float acc[NPB];
    #pragma unroll
    for (int e = 0; e < NPB; ++e) acc[e] = bias2;

    for (int k = 0; k < H; k += 4) {
        float wA = w2l[(k + 0) * H + f];
        float wB = w2l[(k + 1) * H + f];
        float wC = w2l[(k + 2) * H + f];
        float wD = w2l[(k + 3) * H + f];
        #pragma unroll
        for (int e = 0; e < NPB; ++e) {
            float4 t4 = *reinterpret_cast<const float4*>(&as[e][k]);
            acc[e] = fmaf(t4.x, wA, acc[e]);
            acc[e] = fmaf(t4.y, wB, acc[e]);
            acc[e] = fmaf(t4.z, wC, acc[e]);
            acc[e] = fmaf(t4.w, wD, acc[e]);
        }
    }
    #pragma unroll
    for (int e = 0; e < NPB; ++e) ts[e][f] = ssp_fast(acc[e]);
    __syncthreads();

    const float biasL = bl[f];
    float acc2[NPB];
    #pragma unroll
    for (int e = 0; e < NPB; ++e) acc2[e] = biasL;

    for (int k = 0; k < H; k += 4) {
        float wA = wl[(k + 0) * H + f];
        float wB = wl[(k + 1) * H + f];
        float wC = wl[(k + 2) * H + f];
        float wD = wl[(k + 3) * H + f];
        #pragma unroll
        for (int e = 0; e < NPB; ++e) {
            float4 t4 = *reinterpret_cast<const float4*>(&ts[e][k]);
            acc2[e] = fmaf(t4.x, wA, acc2[e]);
            acc2[e] = fmaf(t4.y, wB, acc2[e]);
            acc2[e] = fmaf(t4.z, wC, acc2[e]);
            acc2[e] = fmaf(t4.w, wD, acc2[e]);
        }
    }
    #pragma unroll
    for (int e = 0; e < NPB; ++e) out[(n0 + e) * H + f] = acc2[e];
}

extern "C" void kernel_launch(void* const* d_in, const int* in_sizes, int n_in,
                              void* d_out, int out_size, void* d_ws, size_t ws_size,
                              hipStream_t stream) {
    const float* h      = (const float*)d_in[0];
    const float* pos    = (const float*)d_in[1];
    const int*   ei     = (const int*)  d_in[2];
    const float* mlp_w1 = (const float*)d_in[3];
    const float* mlp_b1 = (const float*)d_in[4];
    const float* mlp_w2 = (const float*)d_in[5];
    const float* mlp_b2 = (const float*)d_in[6];
    const float* lin1_w = (const float*)d_in[7];
    const float* lin2_w = (const float*)d_in[8];
    const float* lin2_b = (const float*)d_in[9];
    const float* lin_w  = (const float*)d_in[10];
    const float* lin_b  = (const float*)d_in[11];

    float* out = (float*)d_out;
    float* agg = (float*)d_ws;   // [N, H] accumulator
    float* x   = out;            // reuse d_out as scratch for lin1 output

    hipMemsetAsync(agg, 0, (size_t)N_NODES * H * sizeof(float), stream);
    lin1_kernel<<<N_NODES / NPB, 128, 0, stream>>>(h, lin1_w, x);
    edge_kernel<<<2560, 256, 0, stream>>>(pos, ei, x, mlp_w1, mlp_b1,
                                          mlp_w2, mlp_b2, agg);
    final_kernel<<<N_NODES / NPB, 128, 0, stream>>>(agg, lin2_w, lin2_b,
                                                    lin_w, lin_b, out);
}